// Round 12
// baseline (132.037 us; speedup 1.0000x reference)
//
#include <hip/hip_runtime.h>
#include <hip/hip_bf16.h>
#include <stdint.h>

#define B_ 2
#define T_ 2048
#define C_ 1024
#define H_ 16
#define HD_ 64
#define NTOK (B_*T_)   // 4096

typedef __bf16 bf16;
typedef bf16 bf16x4 __attribute__((ext_vector_type(4)));
typedef bf16 bf16x8 __attribute__((ext_vector_type(8)));
typedef float f32x4 __attribute__((ext_vector_type(4)));

static __device__ __forceinline__ f32x4 mfma16(bf16x8 a, bf16x8 b, f32x4 c) {
  return __builtin_amdgcn_mfma_f32_16x16x32_bf16(a, b, c, 0, 0, 0);
}

static __device__ __forceinline__ void gload_lds16(const void* g, void* l) {
  __builtin_amdgcn_global_load_lds(
      (__attribute__((address_space(1))) void*)g,
      (__attribute__((address_space(3))) void*)l, 16, 0, 0);
}

static __device__ __forceinline__ uint32_t cvt_pk_bf16(float lo, float hi) {
  uint32_t r;
  asm("v_cvt_pk_bf16_f32 %0, %1, %2" : "=v"(r) : "v"(lo), "v"(hi));
  return r;
}

#define BAR() do { __builtin_amdgcn_sched_barrier(0); __builtin_amdgcn_s_barrier(); __builtin_amdgcn_sched_barrier(0); } while (0)
#define BARV0() do { asm volatile("s_waitcnt vmcnt(0)"); __builtin_amdgcn_sched_barrier(0); __builtin_amdgcn_s_barrier(); __builtin_amdgcn_sched_barrier(0); } while (0)

// ---------------- fused fp32 -> bf16 convert (x + 4 weights, 1 dispatch) ----
__global__ void cvt_all(const float* __restrict__ x,
                        const float* __restrict__ w0, const float* __restrict__ w1,
                        const float* __restrict__ w2, const float* __restrict__ w3,
                        bf16* __restrict__ xb,
                        bf16* __restrict__ d0, bf16* __restrict__ d1,
                        bf16* __restrict__ d2, bf16* __restrict__ d3) {
  const int i = blockIdx.x * 256 + threadIdx.x;  // [0, 256K)
  const int y = blockIdx.y;
  const float* src;
  bf16* dst;
  size_t off4 = 0;
  if (y < 4) {
    src = x; dst = xb; off4 = (size_t)y << 18;  // y * 256K float4
  } else if (y == 4) { src = w0; dst = d0; }
  else if (y == 5)   { src = w1; dst = d1; }
  else if (y == 6)   { src = w2; dst = d2; }
  else               { src = w3; dst = d3; }
  float4 v = reinterpret_cast<const float4*>(src)[off4 + i];
  bf16x4 o;
  o.x = (bf16)v.x; o.y = (bf16)v.y; o.z = (bf16)v.z; o.w = (bf16)v.w;
  reinterpret_cast<bf16x4*>(dst)[off4 + i] = o;
}

// ---------------- QKV GEMM: 256x192 tile, 4-phase pipelined K-loop ----------
// A = xb [4096][1024]; B = Wcat [3072][1024] (wqb|wkb|wvb contiguous in ws).
// grid (16 M-tiles, 16 N-tiles) = 256 blocks = exact chip fill, 1 block/CU.
// 8 waves (2M x 4N), per-wave 128x48 output, acc[8][3] f32x4.
// Per K-tile (BK=64): 4 phases {stage piece of tile T+1 into dbuf nxt ->
// ds_read quadrant operands (cur) -> setprio MFMA -> s_barrier}; one
// vmcnt(0) per tile (phase-issued loads ride across intra-tile barriers).
// LDS: linear gload_lds dest + source-swizzled (slot ^ row&7) per rule #21.
__global__ __launch_bounds__(512) void qkv_gemm(
    const bf16* __restrict__ X, const bf16* __restrict__ Wcat,
    bf16* __restrict__ Q, bf16* __restrict__ K, bf16* __restrict__ VT) {
  __shared__ bf16 As[2][256 * 64];   // 64 KB
  __shared__ bf16 Bs[2][192 * 64];   // 48 KB
  const int tid = threadIdx.x;       // 0..511
  const int lane = tid & 63;
  const int wid = tid >> 6;          // 0..7
  const int wm = wid >> 2, wn = wid & 3;
  const int l15 = lane & 15, lhi = lane >> 4;
  const int M0 = blockIdx.x * 256;
  const int N0 = blockIdx.y * 192;
  const int sr = tid >> 3;           // 0..63 (staging row base)
  const int ss = tid & 7;            // staging 16B slot

  f32x4 acc[8][3] = {};

#define STAGE_A(kt, d, h)                                                          \
  do {                                                                             \
    _Pragma("unroll")                                                              \
    for (int j = 0; j < 2; j++) {                                                  \
      int row = (h) * 128 + sr + j * 64;                                           \
      gload_lds16(X + (size_t)(M0 + row) * C_ + (kt) * 64 + ((ss ^ (row & 7)) * 8),\
                  (char*)&As[d][0] + row * 128 + ss * 16);                         \
    }                                                                              \
  } while (0)

#define STAGE_B(kt, d, c)                                                          \
  do {                                                                             \
    int row = (c) * 64 + sr;                                                       \
    gload_lds16(Wcat + (size_t)(N0 + row) * C_ + (kt) * 64 + ((ss ^ (row & 7)) * 8),\
                (char*)&Bs[d][0] + row * 128 + ss * 16);                           \
  } while (0)

  // prologue: tile 0 fully staged
  STAGE_A(0, 0, 0); STAGE_A(0, 0, 1);
  STAGE_B(0, 0, 0); STAGE_B(0, 0, 1); STAGE_B(0, 0, 2);
  BARV0();

  bf16x8 a[8][2], b[3][2];

  for (int T = 0; T < 16; ++T) {
    const int cur = T & 1, nxt = cur ^ 1;
    const int kn = T + 1;  // T=15 stages harmless mapped OOB (never read)

    // ---- phase a: A-half0 stage; read A mf0-3 + B nf0-1; mfma 16 ----
    STAGE_A(kn, nxt, 0);
#pragma unroll
    for (int mf = 0; mf < 4; mf++) {
      const int row = wm * 128 + mf * 16 + l15;
#pragma unroll
      for (int kk = 0; kk < 2; kk++)
        a[mf][kk] = *reinterpret_cast<const bf16x8*>(
            (const char*)&As[cur][0] + row * 128 + (((kk * 4 + lhi) ^ (row & 7)) * 16));
    }
#pragma unroll
    for (int nf = 0; nf < 2; nf++) {
      const int row = wn * 48 + nf * 16 + l15;
#pragma unroll
      for (int kk = 0; kk < 2; kk++)
        b[nf][kk] = *reinterpret_cast<const bf16x8*>(
            (const char*)&Bs[cur][0] + row * 128 + (((kk * 4 + lhi) ^ (row & 7)) * 16));
    }
    __builtin_amdgcn_s_setprio(1);
#pragma unroll
    for (int mf = 0; mf < 4; mf++)
#pragma unroll
      for (int nf = 0; nf < 2; nf++)
#pragma unroll
        for (int kk = 0; kk < 2; kk++)
          acc[mf][nf] = mfma16(a[mf][kk], b[nf][kk], acc[mf][nf]);
    __builtin_amdgcn_s_setprio(0);
    BAR();

    // ---- phase b: A-half1 stage; read B nf2; mfma 8 ----
    STAGE_A(kn, nxt, 1);
    {
      const int row = wn * 48 + 2 * 16 + l15;
#pragma unroll
      for (int kk = 0; kk < 2; kk++)
        b[2][kk] = *reinterpret_cast<const bf16x8*>(
            (const char*)&Bs[cur][0] + row * 128 + (((kk * 4 + lhi) ^ (row & 7)) * 16));
    }
    __builtin_amdgcn_s_setprio(1);
#pragma unroll
    for (int mf = 0; mf < 4; mf++)
#pragma unroll
      for (int kk = 0; kk < 2; kk++)
        acc[mf][2] = mfma16(a[mf][kk], b[2][kk], acc[mf][2]);
    __builtin_amdgcn_s_setprio(0);
    BAR();

    // ---- phase c: B chunks 0,1 stage; read A mf4-7; mfma 8 ----
    STAGE_B(kn, nxt, 0); STAGE_B(kn, nxt, 1);
#pragma unroll
    for (int mf = 4; mf < 8; mf++) {
      const int row = wm * 128 + mf * 16 + l15;
#pragma unroll
      for (int kk = 0; kk < 2; kk++)
        a[mf][kk] = *reinterpret_cast<const bf16x8*>(
            (const char*)&As[cur][0] + row * 128 + (((kk * 4 + lhi) ^ (row & 7)) * 16));
    }
    __builtin_amdgcn_s_setprio(1);
#pragma unroll
    for (int mf = 4; mf < 8; mf++)
#pragma unroll
      for (int kk = 0; kk < 2; kk++)
        acc[mf][2] = mfma16(a[mf][kk], b[2][kk], acc[mf][2]);
    __builtin_amdgcn_s_setprio(0);
    BAR();

    // ---- phase d: B chunk 2 stage; mfma 16; full drain ----
    STAGE_B(kn, nxt, 2);
    __builtin_amdgcn_s_setprio(1);
#pragma unroll
    for (int mf = 4; mf < 8; mf++)
#pragma unroll
      for (int nf = 0; nf < 2; nf++)
#pragma unroll
        for (int kk = 0; kk < 2; kk++)
          acc[mf][nf] = mfma16(a[mf][kk], b[nf][kk], acc[mf][nf]);
    __builtin_amdgcn_s_setprio(0);
    BARV0();
  }
#undef STAGE_A
#undef STAGE_B

  // epilogue: scatter to Q/K/VT layouts
  const float QSCALE = 0.125f * 1.44269504f;  // hd^-0.5 * log2(e), folded into Q
#pragma unroll
  for (int mf = 0; mf < 8; mf++) {
#pragma unroll
    for (int nf = 0; nf < 3; nf++) {
#pragma unroll
      for (int r = 0; r < 4; r++) {
        int tok = M0 + wm * 128 + mf * 16 + lhi * 4 + r;
        int o = N0 + wn * 48 + nf * 16 + l15;
        int z = o >> 10, oz = o & 1023;
        int h = oz >> 6, d = oz & 63;
        int bb = tok >> 11, t = tok & (T_ - 1);
        float v = acc[mf][nf][r];
        if (z == 0) {
          Q[((size_t)(bb * H_ + h) * T_ + t) * HD_ + d] = (bf16)(v * QSCALE);
        } else if (z == 1) {
          K[((size_t)(bb * H_ + h) * T_ + t) * HD_ + d] = (bf16)v;
        } else {
          VT[((size_t)(bb * H_ + h) * HD_ + d) * T_ + t] = (bf16)v;
        }
      }
    }
  }
}

// ---------------- causal flash attention (round-10 body, unchanged) ----------
__global__ __launch_bounds__(256, 3) void attn_kernel(
    const bf16* __restrict__ Q, const bf16* __restrict__ K,
    const bf16* __restrict__ VT, bf16* __restrict__ att) {
  __shared__ bf16 Kt[2][64 * 64];   // [buf][row*64 + col] (swizzled chunks)
  __shared__ bf16 Vt[2][64 * 64];   // [buf][d*64 + t]
  __shared__ bf16 P[4][32][72];     // per-wave P, row=q (32), 144B row stride
  const int tid = threadIdx.x;
  const int lane = tid & 63;
  const int w = tid >> 6;           // 0..3
  const int l15 = lane & 15, lhi = lane >> 4;
  const int bh = blockIdx.x;
  const int b = bh >> 4, h = bh & 15;
  const int by = (int)blockIdx.y;
  const int qt = (by < 8) ? (15 - by) : (by - 8);  // balanced co-residency pairs
  const int qw0 = qt * 128 + w * 32;
  const bf16* Qb = Q + (size_t)bh * T_ * HD_;
  const bf16* Kb = K + (size_t)bh * T_ * HD_;
  const bf16* Vb = VT + (size_t)bh * HD_ * T_;

  bf16x8 q[2][2];
#pragma unroll
  for (int m = 0; m < 2; m++)
#pragma unroll
    for (int kk = 0; kk < 2; kk++)
      q[m][kk] = *reinterpret_cast<const bf16x8*>(
          &Qb[(size_t)(qw0 + m * 16 + l15) * HD_ + kk * 32 + lhi * 8]);

  f32x4 o_acc[2][4] = {};
  float lsum[2] = {0.f, 0.f};

  const int nt = 2 * qt + 2;  // kv tiles for this block

  const int c0 = tid, c1 = tid + 256;
  const int r0 = c0 >> 3, x0 = (c0 & 7) ^ (r0 & 7);
  const int r1 = c1 >> 3, x1 = (c1 & 7) ^ (r1 & 7);

#define STAGE(tt, bb)                                                                \
  do {                                                                               \
    int kv = (tt) * 64;                                                              \
    gload_lds16(Kb + (size_t)(kv + r0) * HD_ + x0 * 8, (char*)&Kt[bb][0] + c0 * 16); \
    gload_lds16(Kb + (size_t)(kv + r1) * HD_ + x1 * 8, (char*)&Kt[bb][0] + c1 * 16); \
    gload_lds16(Vb + (size_t)r0 * T_ + kv + x0 * 8, (char*)&Vt[bb][0] + c0 * 16);    \
    gload_lds16(Vb + (size_t)r1 * T_ + kv + x1 * 8, (char*)&Vt[bb][0] + c1 * 16);    \
  } while (0)

  STAGE(0, 0);
  __syncthreads();
  int cur = 0;

  for (int it = 0; it < nt; ++it) {
    const int kv0 = it * 64;
    if (it + 1 < nt) STAGE(it + 1, cur ^ 1);

    if (kv0 <= qw0 + 31) {  // wave-uniform: skip fully-masked tiles
      f32x4 s[2][4] = {};
#pragma unroll
      for (int n = 0; n < 4; n++) {
        const int krow = n * 16 + l15;
#pragma unroll
        for (int kk = 0; kk < 2; kk++) {
          const int kx = (kk * 4 + lhi) ^ (l15 & 7);
          bf16x8 kf = *reinterpret_cast<const bf16x8*>(
              (const char*)&Kt[cur][0] + krow * 128 + kx * 16);
          s[0][n] = mfma16(kf, q[0][kk], s[0][n]);
          s[1][n] = mfma16(kf, q[1][kk], s[1][n]);
        }
      }

      if (kv0 + 63 > qw0) {  // boundary tiles: causal mask (key > query)
#pragma unroll
        for (int m = 0; m < 2; m++) {
          const int qrow = qw0 + m * 16 + l15;
#pragma unroll
          for (int n = 0; n < 4; n++) {
            const int key = kv0 + n * 16 + lhi * 4;
#pragma unroll
            for (int r = 0; r < 4; r++) {
              if (key + r > qrow) s[m][n][r] = -1e30f;
            }
          }
        }
      }
#pragma unroll
      for (int m = 0; m < 2; m++) {
        char* pw = (char*)&P[w][m * 16 + l15][0];
#pragma unroll
        for (int n = 0; n < 4; n++) {
          float p0 = __builtin_amdgcn_exp2f(s[m][n][0]);
          float p1 = __builtin_amdgcn_exp2f(s[m][n][1]);
          float p2 = __builtin_amdgcn_exp2f(s[m][n][2]);
          float p3 = __builtin_amdgcn_exp2f(s[m][n][3]);
          lsum[m] += (p0 + p1) + (p2 + p3);
          uint32_t lo = cvt_pk_bf16(p0, p1);
          uint32_t hi = cvt_pk_bf16(p2, p3);
          *reinterpret_cast<uint2*>(pw + (4 * n + lhi) * 8) = make_uint2(lo, hi);
        }
      }
      bf16x8 pa[2][2];
#pragma unroll
      for (int m = 0; m < 2; m++)
#pragma unroll
        for (int kk = 0; kk < 2; kk++)
          pa[m][kk] = *reinterpret_cast<const bf16x8*>(
              (const char*)&P[w][m * 16 + l15][0] + kk * 64 + lhi * 16);
#pragma unroll
      for (int n = 0; n < 4; n++) {
        const int vrow = n * 16 + l15;
#pragma unroll
        for (int kk = 0; kk < 2; kk++) {
          const int vx = (kk * 4 + lhi) ^ (l15 & 7);
          bf16x8 vf = *reinterpret_cast<const bf16x8*>(
              (const char*)&Vt[cur][0] + vrow * 128 + vx * 16);
          o_acc[0][n] = mfma16(pa[0][kk], vf, o_acc[0][n]);
          o_acc[1][n] = mfma16(pa[1][kk], vf, o_acc[1][n]);
        }
      }
    }
    __syncthreads();
    cur ^= 1;
  }
#undef STAGE

  float lred[2];
#pragma unroll
  for (int m = 0; m < 2; m++) {
    float v = lsum[m];
    v += __shfl_xor(v, 16);
    v += __shfl_xor(v, 32);
    lred[m] = v;
  }
#pragma unroll
  for (int m = 0; m < 2; m++) {
#pragma unroll
    for (int r = 0; r < 4; r++) {
      float rs = __shfl(lred[m], (lane & 48) + lhi * 4 + r);
      float li = 1.f / rs;
      int t = qw0 + m * 16 + lhi * 4 + r;
#pragma unroll
      for (int n = 0; n < 4; n++) {
        int d = n * 16 + l15;
        att[((size_t)(b * T_ + t) * H_ + h) * HD_ + d] = (bf16)(o_acc[m][n][r] * li);
      }
    }
  }
}

// ---------------- output projection: out = att @ Wp.T + bp ----------------
__global__ __launch_bounds__(256) void proj_gemm(
    const bf16* __restrict__ A, const bf16* __restrict__ Wp,
    const float* __restrict__ bp, float* __restrict__ out) {
  __shared__ bf16 As[128 * 32];
  __shared__ bf16 Bs[128 * 32];
  const int n0 = blockIdx.x * 128;
  const int o0 = blockIdx.y * 128;
  const int tid = threadIdx.x;
  const int lane = tid & 63;
  const int w = tid >> 6;
  const int wr = w >> 1, wc = w & 1;
  const int l15 = lane & 15, lhi = lane >> 4;

  f32x4 acc[4][4] = {};

  const int ca = tid;
  const int cb = tid + 256;
  const int rowa = ca >> 2, cola = (ca & 3) * 8;
  const int rowb = cb >> 2, colb = (cb & 3) * 8;

  for (int k0 = 0; k0 < C_; k0 += 32) {
    __syncthreads();
    gload_lds16(A + (size_t)(n0 + rowa) * C_ + k0 + cola, (char*)As + ca * 16);
    gload_lds16(A + (size_t)(n0 + rowb) * C_ + k0 + colb, (char*)As + cb * 16);
    gload_lds16(Wp + (size_t)(o0 + rowa) * C_ + k0 + cola, (char*)Bs + ca * 16);
    gload_lds16(Wp + (size_t)(o0 + rowb) * C_ + k0 + colb, (char*)Bs + cb * 16);
    __syncthreads();
    bf16x8 a[4], b[4];
#pragma unroll
    for (int m = 0; m < 4; m++)
      a[m] = *reinterpret_cast<const bf16x8*>(&As[(wr * 64 + m * 16 + l15) * 32 + lhi * 8]);
#pragma unroll
    for (int n = 0; n < 4; n++)
      b[n] = *reinterpret_cast<const bf16x8*>(&Bs[(wc * 64 + n * 16 + l15) * 32 + lhi * 8]);
#pragma unroll
    for (int m = 0; m < 4; m++)
#pragma unroll
      for (int n = 0; n < 4; n++)
        acc[m][n] = mfma16(a[m], b[n], acc[m][n]);
  }

#pragma unroll
  for (int m = 0; m < 4; m++) {
#pragma unroll
    for (int n = 0; n < 4; n++) {
#pragma unroll
      for (int r = 0; r < 4; r++) {
        int tok = n0 + wr * 64 + m * 16 + lhi * 4 + r;
        int o = o0 + wc * 64 + n * 16 + l15;
        out[(size_t)tok * C_ + o] = acc[m][n][r] + bp[o];
      }
    }
  }
}

extern "C" void kernel_launch(void* const* d_in, const int* in_sizes, int n_in,
                              void* d_out, int out_size, void* d_ws, size_t ws_size,
                              hipStream_t stream) {
  const float* x  = (const float*)d_in[0];
  const float* Wq = (const float*)d_in[1];
  const float* Wk = (const float*)d_in[2];
  const float* Wv = (const float*)d_in[3];
  const float* Wp = (const float*)d_in[4];
  const float* bp = (const float*)d_in[5];
  float* out = (float*)d_out;

  char* ws = (char*)d_ws;
  size_t off = 0;
  bf16* xb  = (bf16*)(ws + off); off += (size_t)NTOK * C_ * 2;
  bf16* wqb = (bf16*)(ws + off); off += (size_t)C_ * C_ * 2;  // wqb|wkb|wvb contiguous = Wcat
  bf16* wkb = (bf16*)(ws + off); off += (size_t)C_ * C_ * 2;
  bf16* wvb = (bf16*)(ws + off); off += (size_t)C_ * C_ * 2;
  bf16* wpb = (bf16*)(ws + off); off += (size_t)C_ * C_ * 2;
  bf16* Qd  = (bf16*)(ws + off); off += (size_t)NTOK * C_ * 2;
  bf16* Kd  = (bf16*)(ws + off); off += (size_t)NTOK * C_ * 2;
  bf16* VTd = (bf16*)(ws + off); off += (size_t)NTOK * C_ * 2;
  bf16* att = (bf16*)(ws + off); off += (size_t)NTOK * C_ * 2;
  (void)ws_size; (void)out_size; (void)in_sizes; (void)n_in;

  cvt_all<<<dim3(1024, 8), 256, 0, stream>>>(x, Wq, Wk, Wv, Wp, xb, wqb, wkb, wvb, wpb);

  qkv_gemm<<<dim3(16, 16), 512, 0, stream>>>(xb, wqb, Qd, Kd, VTd);
  attn_kernel<<<dim3(B_ * H_, 16), 256, 0, stream>>>(Qd, Kd, VTd, att);
  proj_gemm<<<dim3(NTOK / 128, C_ / 128), 256, 0, stream>>>(att, wpb, bp, out);
}

// Round 13
// 111.456 us; speedup vs baseline: 1.1847x; 1.1847x over previous
//
#include <hip/hip_runtime.h>
#include <hip/hip_bf16.h>
#include <stdint.h>

#define B_ 2
#define T_ 2048
#define C_ 1024
#define H_ 16
#define HD_ 64
#define NTOK (B_*T_)   // 4096

typedef __bf16 bf16;
typedef bf16 bf16x4 __attribute__((ext_vector_type(4)));
typedef bf16 bf16x8 __attribute__((ext_vector_type(8)));
typedef float f32x4 __attribute__((ext_vector_type(4)));

static __device__ __forceinline__ f32x4 mfma16(bf16x8 a, bf16x8 b, f32x4 c) {
  return __builtin_amdgcn_mfma_f32_16x16x32_bf16(a, b, c, 0, 0, 0);
}

static __device__ __forceinline__ void gload_lds16(const void* g, void* l) {
  __builtin_amdgcn_global_load_lds(
      (__attribute__((address_space(1))) void*)g,
      (__attribute__((address_space(3))) void*)l, 16, 0, 0);
}

static __device__ __forceinline__ uint32_t cvt_pk_bf16(float lo, float hi) {
  uint32_t r;
  asm("v_cvt_pk_bf16_f32 %0, %1, %2" : "=v"(r) : "v"(lo), "v"(hi));
  return r;
}

// ---------------- fused fp32 -> bf16 convert (x + 4 weights, 1 dispatch) ----
__global__ void cvt_all(const float* __restrict__ x,
                        const float* __restrict__ w0, const float* __restrict__ w1,
                        const float* __restrict__ w2, const float* __restrict__ w3,
                        bf16* __restrict__ xb,
                        bf16* __restrict__ d0, bf16* __restrict__ d1,
                        bf16* __restrict__ d2, bf16* __restrict__ d3) {
  const int i = blockIdx.x * 256 + threadIdx.x;  // [0, 256K)
  const int y = blockIdx.y;
  const float* src;
  bf16* dst;
  size_t off4 = 0;
  if (y < 4) {
    src = x; dst = xb; off4 = (size_t)y << 18;  // y * 256K float4
  } else if (y == 4) { src = w0; dst = d0; }
  else if (y == 5)   { src = w1; dst = d1; }
  else if (y == 6)   { src = w2; dst = d2; }
  else               { src = w3; dst = d3; }
  float4 v = reinterpret_cast<const float4*>(src)[off4 + i];
  bf16x4 o;
  o.x = (bf16)v.x; o.y = (bf16)v.y; o.z = (bf16)v.z; o.w = (bf16)v.w;
  reinterpret_cast<bf16x4*>(dst)[off4 + i] = o;
}

// ---------------- QKV GEMM: y = x @ W.T (128x128 tile, BK=64, swizzled) ----
// r10 skeleton (single-buffer, stage-all-at-top, 2 barriers/K-step, multi-
// block/CU implicit pipelining) with BK doubled 32->64 (halves barrier+drain
// events) and the r12-verified XOR swizzle (0 bank conflicts at 128B row
// stride). Default blockIdx mapping (explicit XCD swizzle regressed in r9).
__global__ __launch_bounds__(256) void qkv_gemm(
    const bf16* __restrict__ X,
    const bf16* __restrict__ Wq, const bf16* __restrict__ Wk, const bf16* __restrict__ Wv,
    bf16* __restrict__ Q, bf16* __restrict__ K, bf16* __restrict__ VT) {
  __shared__ bf16 As[128 * 64];   // 16 KB, row stride 128 B
  __shared__ bf16 Bs[128 * 64];   // 16 KB
  const int z = blockIdx.z;
  const bf16* W = (z == 0) ? Wq : (z == 1) ? Wk : Wv;
  const int n0 = blockIdx.x * 128;  // token tile
  const int o0 = blockIdx.y * 128;  // out-feature tile
  const int tid = threadIdx.x;
  const int lane = tid & 63;
  const int w = tid >> 6;
  const int wr = w >> 1, wc = w & 1;
  const int l15 = lane & 15, lhi = lane >> 4;
  const int x7 = l15 & 7;

  f32x4 acc[4][4] = {};

  for (int k0 = 0; k0 < C_; k0 += 64) {
    __syncthreads();
#pragma unroll
    for (int j = 0; j < 4; j++) {
      const int c = tid + j * 256;          // 16B-chunk id, 0..1023
      const int row = c >> 3;               // 0..127
      const int scol = ((c & 7) ^ (row & 7)) * 8;
      gload_lds16(X + (size_t)(n0 + row) * C_ + k0 + scol, (char*)As + c * 16);
      gload_lds16(W + (size_t)(o0 + row) * C_ + k0 + scol, (char*)Bs + c * 16);
    }
    __syncthreads();
    bf16x8 a[4][2], b[4][2];
#pragma unroll
    for (int m = 0; m < 4; m++) {
      const int row = wr * 64 + m * 16 + l15;
#pragma unroll
      for (int kk = 0; kk < 2; kk++)
        a[m][kk] = *reinterpret_cast<const bf16x8*>(
            (const char*)As + row * 128 + (((kk * 4 + lhi) ^ x7) * 16));
    }
#pragma unroll
    for (int n = 0; n < 4; n++) {
      const int row = wc * 64 + n * 16 + l15;
#pragma unroll
      for (int kk = 0; kk < 2; kk++)
        b[n][kk] = *reinterpret_cast<const bf16x8*>(
            (const char*)Bs + row * 128 + (((kk * 4 + lhi) ^ x7) * 16));
    }
#pragma unroll
    for (int m = 0; m < 4; m++)
#pragma unroll
      for (int n = 0; n < 4; n++)
#pragma unroll
        for (int kk = 0; kk < 2; kk++)
          acc[m][n] = mfma16(a[m][kk], b[n][kk], acc[m][n]);
  }

  const float QSCALE = 0.125f * 1.44269504f;  // hd^-0.5 * log2(e), folded into Q
#pragma unroll
  for (int m = 0; m < 4; m++) {
#pragma unroll
    for (int n = 0; n < 4; n++) {
#pragma unroll
      for (int r = 0; r < 4; r++) {
        int tok = n0 + wr * 64 + m * 16 + lhi * 4 + r;
        int o = o0 + wc * 64 + n * 16 + l15;
        int bb = tok >> 11, t = tok & (T_ - 1);
        int h = o >> 6, d = o & 63;
        float v = acc[m][n][r];
        if (z == 0) {
          Q[((size_t)(bb * H_ + h) * T_ + t) * HD_ + d] = (bf16)(v * QSCALE);
        } else if (z == 1) {
          K[((size_t)(bb * H_ + h) * T_ + t) * HD_ + d] = (bf16)v;
        } else {
          VT[((size_t)(bb * H_ + h) * HD_ + d) * T_ + t] = (bf16)v;
        }
      }
    }
  }
}

// ---------------- causal flash attention (round-10 body, unchanged) ----------
__global__ __launch_bounds__(256, 3) void attn_kernel(
    const bf16* __restrict__ Q, const bf16* __restrict__ K,
    const bf16* __restrict__ VT, bf16* __restrict__ att) {
  __shared__ bf16 Kt[2][64 * 64];   // [buf][row*64 + col] (swizzled chunks)
  __shared__ bf16 Vt[2][64 * 64];   // [buf][d*64 + t]
  __shared__ bf16 P[4][32][72];     // per-wave P, row=q (32), 144B row stride
  const int tid = threadIdx.x;
  const int lane = tid & 63;
  const int w = tid >> 6;           // 0..3
  const int l15 = lane & 15, lhi = lane >> 4;
  const int bh = blockIdx.x;
  const int b = bh >> 4, h = bh & 15;
  const int by = (int)blockIdx.y;
  const int qt = (by < 8) ? (15 - by) : (by - 8);  // balanced co-residency pairs
  const int qw0 = qt * 128 + w * 32;
  const bf16* Qb = Q + (size_t)bh * T_ * HD_;
  const bf16* Kb = K + (size_t)bh * T_ * HD_;
  const bf16* Vb = VT + (size_t)bh * HD_ * T_;

  bf16x8 q[2][2];
#pragma unroll
  for (int m = 0; m < 2; m++)
#pragma unroll
    for (int kk = 0; kk < 2; kk++)
      q[m][kk] = *reinterpret_cast<const bf16x8*>(
          &Qb[(size_t)(qw0 + m * 16 + l15) * HD_ + kk * 32 + lhi * 8]);

  f32x4 o_acc[2][4] = {};
  float lsum[2] = {0.f, 0.f};

  const int nt = 2 * qt + 2;  // kv tiles for this block

  const int c0 = tid, c1 = tid + 256;
  const int r0 = c0 >> 3, x0 = (c0 & 7) ^ (r0 & 7);
  const int r1 = c1 >> 3, x1 = (c1 & 7) ^ (r1 & 7);

#define STAGE(tt, bb)                                                                \
  do {                                                                               \
    int kv = (tt) * 64;                                                              \
    gload_lds16(Kb + (size_t)(kv + r0) * HD_ + x0 * 8, (char*)&Kt[bb][0] + c0 * 16); \
    gload_lds16(Kb + (size_t)(kv + r1) * HD_ + x1 * 8, (char*)&Kt[bb][0] + c1 * 16); \
    gload_lds16(Vb + (size_t)r0 * T_ + kv + x0 * 8, (char*)&Vt[bb][0] + c0 * 16);    \
    gload_lds16(Vb + (size_t)r1 * T_ + kv + x1 * 8, (char*)&Vt[bb][0] + c1 * 16);    \
  } while (0)

  STAGE(0, 0);
  __syncthreads();
  int cur = 0;

  for (int it = 0; it < nt; ++it) {
    const int kv0 = it * 64;
    if (it + 1 < nt) STAGE(it + 1, cur ^ 1);

    if (kv0 <= qw0 + 31) {  // wave-uniform: skip fully-masked tiles
      f32x4 s[2][4] = {};
#pragma unroll
      for (int n = 0; n < 4; n++) {
        const int krow = n * 16 + l15;
#pragma unroll
        for (int kk = 0; kk < 2; kk++) {
          const int kx = (kk * 4 + lhi) ^ (l15 & 7);
          bf16x8 kf = *reinterpret_cast<const bf16x8*>(
              (const char*)&Kt[cur][0] + krow * 128 + kx * 16);
          s[0][n] = mfma16(kf, q[0][kk], s[0][n]);
          s[1][n] = mfma16(kf, q[1][kk], s[1][n]);
        }
      }

      if (kv0 + 63 > qw0) {  // boundary tiles: causal mask (key > query)
#pragma unroll
        for (int m = 0; m < 2; m++) {
          const int qrow = qw0 + m * 16 + l15;
#pragma unroll
          for (int n = 0; n < 4; n++) {
            const int key = kv0 + n * 16 + lhi * 4;
#pragma unroll
            for (int r = 0; r < 4; r++) {
              if (key + r > qrow) s[m][n][r] = -1e30f;
            }
          }
        }
      }
#pragma unroll
      for (int m = 0; m < 2; m++) {
        char* pw = (char*)&P[w][m * 16 + l15][0];
#pragma unroll
        for (int n = 0; n < 4; n++) {
          float p0 = __builtin_amdgcn_exp2f(s[m][n][0]);
          float p1 = __builtin_amdgcn_exp2f(s[m][n][1]);
          float p2 = __builtin_amdgcn_exp2f(s[m][n][2]);
          float p3 = __builtin_amdgcn_exp2f(s[m][n][3]);
          lsum[m] += (p0 + p1) + (p2 + p3);
          uint32_t lo = cvt_pk_bf16(p0, p1);
          uint32_t hi = cvt_pk_bf16(p2, p3);
          *reinterpret_cast<uint2*>(pw + (4 * n + lhi) * 8) = make_uint2(lo, hi);
        }
      }
      bf16x8 pa[2][2];
#pragma unroll
      for (int m = 0; m < 2; m++)
#pragma unroll
        for (int kk = 0; kk < 2; kk++)
          pa[m][kk] = *reinterpret_cast<const bf16x8*>(
              (const char*)&P[w][m * 16 + l15][0] + kk * 64 + lhi * 16);
#pragma unroll
      for (int n = 0; n < 4; n++) {
        const int vrow = n * 16 + l15;
#pragma unroll
        for (int kk = 0; kk < 2; kk++) {
          const int vx = (kk * 4 + lhi) ^ (l15 & 7);
          bf16x8 vf = *reinterpret_cast<const bf16x8*>(
              (const char*)&Vt[cur][0] + vrow * 128 + vx * 16);
          o_acc[0][n] = mfma16(pa[0][kk], vf, o_acc[0][n]);
          o_acc[1][n] = mfma16(pa[1][kk], vf, o_acc[1][n]);
        }
      }
    }
    __syncthreads();
    cur ^= 1;
  }
#undef STAGE

  float lred[2];
#pragma unroll
  for (int m = 0; m < 2; m++) {
    float v = lsum[m];
    v += __shfl_xor(v, 16);
    v += __shfl_xor(v, 32);
    lred[m] = v;
  }
#pragma unroll
  for (int m = 0; m < 2; m++) {
#pragma unroll
    for (int r = 0; r < 4; r++) {
      float rs = __shfl(lred[m], (lane & 48) + lhi * 4 + r);
      float li = 1.f / rs;
      int t = qw0 + m * 16 + lhi * 4 + r;
#pragma unroll
      for (int n = 0; n < 4; n++) {
        int d = n * 16 + l15;
        att[((size_t)(b * T_ + t) * H_ + h) * HD_ + d] = (bf16)(o_acc[m][n][r] * li);
      }
    }
  }
}

// ---------------- output projection (128x128, BK=64, swizzled) ----------
__global__ __launch_bounds__(256) void proj_gemm(
    const bf16* __restrict__ A, const bf16* __restrict__ Wp,
    const float* __restrict__ bp, float* __restrict__ out) {
  __shared__ bf16 As[128 * 64];
  __shared__ bf16 Bs[128 * 64];
  const int n0 = blockIdx.x * 128;
  const int o0 = blockIdx.y * 128;
  const int tid = threadIdx.x;
  const int lane = tid & 63;
  const int w = tid >> 6;
  const int wr = w >> 1, wc = w & 1;
  const int l15 = lane & 15, lhi = lane >> 4;
  const int x7 = l15 & 7;

  f32x4 acc[4][4] = {};

  for (int k0 = 0; k0 < C_; k0 += 64) {
    __syncthreads();
#pragma unroll
    for (int j = 0; j < 4; j++) {
      const int c = tid + j * 256;
      const int row = c >> 3;
      const int scol = ((c & 7) ^ (row & 7)) * 8;
      gload_lds16(A + (size_t)(n0 + row) * C_ + k0 + scol, (char*)As + c * 16);
      gload_lds16(Wp + (size_t)(o0 + row) * C_ + k0 + scol, (char*)Bs + c * 16);
    }
    __syncthreads();
    bf16x8 a[4][2], b[4][2];
#pragma unroll
    for (int m = 0; m < 4; m++) {
      const int row = wr * 64 + m * 16 + l15;
#pragma unroll
      for (int kk = 0; kk < 2; kk++)
        a[m][kk] = *reinterpret_cast<const bf16x8*>(
            (const char*)As + row * 128 + (((kk * 4 + lhi) ^ x7) * 16));
    }
#pragma unroll
    for (int n = 0; n < 4; n++) {
      const int row = wc * 64 + n * 16 + l15;
#pragma unroll
      for (int kk = 0; kk < 2; kk++)
        b[n][kk] = *reinterpret_cast<const bf16x8*>(
            (const char*)Bs + row * 128 + (((kk * 4 + lhi) ^ x7) * 16));
    }
#pragma unroll
    for (int m = 0; m < 4; m++)
#pragma unroll
      for (int n = 0; n < 4; n++)
#pragma unroll
        for (int kk = 0; kk < 2; kk++)
          acc[m][n] = mfma16(a[m][kk], b[n][kk], acc[m][n]);
  }

#pragma unroll
  for (int m = 0; m < 4; m++) {
#pragma unroll
    for (int n = 0; n < 4; n++) {
#pragma unroll
      for (int r = 0; r < 4; r++) {
        int tok = n0 + wr * 64 + m * 16 + lhi * 4 + r;
        int o = o0 + wc * 64 + n * 16 + l15;
        out[(size_t)tok * C_ + o] = acc[m][n][r] + bp[o];
      }
    }
  }
}

extern "C" void kernel_launch(void* const* d_in, const int* in_sizes, int n_in,
                              void* d_out, int out_size, void* d_ws, size_t ws_size,
                              hipStream_t stream) {
  const float* x  = (const float*)d_in[0];
  const float* Wq = (const float*)d_in[1];
  const float* Wk = (const float*)d_in[2];
  const float* Wv = (const float*)d_in[3];
  const float* Wp = (const float*)d_in[4];
  const float* bp = (const float*)d_in[5];
  float* out = (float*)d_out;

  char* ws = (char*)d_ws;
  size_t off = 0;
  bf16* xb  = (bf16*)(ws + off); off += (size_t)NTOK * C_ * 2;
  bf16* wqb = (bf16*)(ws + off); off += (size_t)C_ * C_ * 2;
  bf16* wkb = (bf16*)(ws + off); off += (size_t)C_ * C_ * 2;
  bf16* wvb = (bf16*)(ws + off); off += (size_t)C_ * C_ * 2;
  bf16* wpb = (bf16*)(ws + off); off += (size_t)C_ * C_ * 2;
  bf16* Qd  = (bf16*)(ws + off); off += (size_t)NTOK * C_ * 2;
  bf16* Kd  = (bf16*)(ws + off); off += (size_t)NTOK * C_ * 2;
  bf16* VTd = (bf16*)(ws + off); off += (size_t)NTOK * C_ * 2;
  bf16* att = (bf16*)(ws + off); off += (size_t)NTOK * C_ * 2;
  (void)ws_size; (void)out_size; (void)in_sizes; (void)n_in;

  cvt_all<<<dim3(1024, 8), 256, 0, stream>>>(x, Wq, Wk, Wv, Wp, xb, wqb, wkb, wvb, wpb);

  qkv_gemm<<<dim3(NTOK / 128, C_ / 128, 3), 256, 0, stream>>>(xb, wqb, wkb, wvb, Qd, Kd, VTd);
  attn_kernel<<<dim3(B_ * H_, 16), 256, 0, stream>>>(Qd, Kd, VTd, att);
  proj_gemm<<<dim3(NTOK / 128, C_ / 128), 256, 0, stream>>>(att, wpb, bp, out);
}